// Round 3
// baseline (650.835 us; speedup 1.0000x reference)
//
#include <hip/hip_runtime.h>
#include <hip/hip_bf16.h>

// Problem dims (fixed by setup_inputs)
#define Mdim 32
#define Kdim 8192
#define Ndim 14336
#define GSZ  128
#define NGRP 64      // Kdim / GSZ

#define KB 8         // K-split factor (chunks of the K dim across blockIdx.y)
#define KC (Kdim/KB) // 1024 = 8 groups of 128
#define BN 64        // n-columns per workgroup (2 waves x 32 cols)

typedef __attribute__((ext_vector_type(16))) float f32x16;
typedef __attribute__((ext_vector_type(8)))  short bf16x8;
typedef __attribute__((ext_vector_type(4)))  int   i32x4;

// ---------------------------------------------------------------------------
// Kernel 1: per-row asymmetric 8-bit quant of x -> (qx - zp) as exact bf16
// integers + per-row scale. One workgroup (256 thr) per row, float4-vector.
// ---------------------------------------------------------------------------
__global__ __launch_bounds__(256) void quant_rows_kernel(
        const float* __restrict__ x,
        __hip_bfloat16* __restrict__ xq,
        float* __restrict__ scales) {
    const int row = blockIdx.x;
    const float4* __restrict__ xr4 = (const float4*)(x + (size_t)row * Kdim);

    float lmin = 3.4e38f, lmax = -3.4e38f;
#pragma unroll
    for (int i = 0; i < Kdim / 4 / 256; ++i) {           // 8 float4 per thread
        const float4 v = xr4[threadIdx.x + i * 256];
        lmin = fminf(lmin, fminf(fminf(v.x, v.y), fminf(v.z, v.w)));
        lmax = fmaxf(lmax, fmaxf(fmaxf(v.x, v.y), fmaxf(v.z, v.w)));
    }
#pragma unroll
    for (int off = 32; off > 0; off >>= 1) {
        lmin = fminf(lmin, __shfl_xor(lmin, off, 64));
        lmax = fmaxf(lmax, __shfl_xor(lmax, off, 64));
    }
    __shared__ float smin[4], smax[4];
    const int wid = threadIdx.x >> 6;
    if ((threadIdx.x & 63) == 0) { smin[wid] = lmin; smax[wid] = lmax; }
    __syncthreads();
    const float xmin = fminf(fminf(smin[0], smin[1]), fminf(smin[2], smin[3]));
    const float xmax = fmaxf(fmaxf(smax[0], smax[1]), fmaxf(smax[2], smax[3]));

    const float scale = fmaxf((xmax - xmin) / 255.0f, 1e-8f);
    float zp = rintf(-128.0f - xmin / scale);   // jnp.round == rintf (half-even)
    zp = fminf(fmaxf(zp, -128.0f), 127.0f);
    if (threadIdx.x == 0) scales[row] = scale;

    ushort4* __restrict__ xq4 = (ushort4*)(xq + (size_t)row * Kdim);
#pragma unroll
    for (int i = 0; i < Kdim / 4 / 256; ++i) {
        const float4 v = xr4[threadIdx.x + i * 256];
        ushort4 o;
        float q;
        q = fminf(fmaxf(rintf(v.x / scale) + zp, -128.0f), 127.0f);
        o.x = __bfloat16_as_ushort(__float2bfloat16(q - zp)); // exact: |.|<=255
        q = fminf(fmaxf(rintf(v.y / scale) + zp, -128.0f), 127.0f);
        o.y = __bfloat16_as_ushort(__float2bfloat16(q - zp));
        q = fminf(fmaxf(rintf(v.z / scale) + zp, -128.0f), 127.0f);
        o.z = __bfloat16_as_ushort(__float2bfloat16(q - zp));
        q = fminf(fmaxf(rintf(v.w / scale) + zp, -128.0f), 127.0f);
        o.w = __bfloat16_as_ushort(__float2bfloat16(q - zp));
        xq4[threadIdx.x + i * 256] = o;
    }
}

// ---------------------------------------------------------------------------
// Kernel 2: the streaming GEMM. grid = (Ndim/BN = 224, KB = 8), 128 threads
// (2 waves) -> 1792 blocks = 7/CU = 14 waves/CU. Each wave: 32x32 output tile
// (all 32 m-rows x 32 n-cols), K-chunk of 1024. B fragments dequantized on
// the fly to bf16 (fma(q, ws, -8ws) + rn-pack). Plain cached weight loads:
// lane c and lane c+32 split each 64B line; L1 merges within the instruction
// pair. Epilogue: RAW partial tile -> nontemporal stores into ws (no atomics,
// no read-modify-write tail); reduce_kernel folds scales/bias afterwards.
// MFMA fragment layouts (gfx950, 32x32x16 bf16):
//   A: row = lane&31, k = 8*(lane>>5)+e   (8 contiguous bf16 per lane)
//   B: col = lane&31, k = 8*(lane>>5)+e
//   C/D: col = lane&31, row = (reg&3) + 8*(reg>>2) + 4*(lane>>5)
// ---------------------------------------------------------------------------
__global__ __launch_bounds__(128) void qlin_main_kernel(
        const int* __restrict__ qw, const float* __restrict__ wscale,
        const __hip_bfloat16* __restrict__ xq,
        float* __restrict__ partials) {
    const int lane  = threadIdx.x & 63;
    const int wid   = threadIdx.x >> 6;
    const int col   = blockIdx.x * BN + wid * 32 + (lane & 31);
    const int k0    = blockIdx.y * KC;
    const int khalf = (lane >> 5) * 8;

    const int* __restrict__ wp = qw + (size_t)col * Kdim + k0 + khalf;
    const __hip_bfloat16* __restrict__ ap =
        xq + (size_t)(lane & 31) * Kdim + k0 + khalf;
    const float* __restrict__ wsp = wscale + (size_t)col * NGRP + (k0 / GSZ);

    f32x16 acc = {};

    for (int g = 0; g < KC / GSZ; ++g) {          // 8 weight groups per chunk
        const float ws   = wsp[g];
        const float m8ws = -8.0f * ws;
        const int* __restrict__ wpg = wp + g * GSZ;
        const __hip_bfloat16* __restrict__ apg = ap + g * GSZ;
#pragma unroll
        for (int s = 0; s < GSZ / 16; ++s) {      // 8 MFMA K-steps per group
            const i32x4 q0 = *(const i32x4*)(wpg + s * 16);
            const i32x4 q1 = *(const i32x4*)(wpg + s * 16 + 4);
            const bf16x8 a = *(const bf16x8*)(apg + s * 16);  // L2-resident

            union { bf16x8 v; __hip_bfloat162 h[4]; } bu;
            const float f0 = fmaf((float)q0[0], ws, m8ws);
            const float f1 = fmaf((float)q0[1], ws, m8ws);
            const float f2 = fmaf((float)q0[2], ws, m8ws);
            const float f3 = fmaf((float)q0[3], ws, m8ws);
            const float f4 = fmaf((float)q1[0], ws, m8ws);
            const float f5 = fmaf((float)q1[1], ws, m8ws);
            const float f6 = fmaf((float)q1[2], ws, m8ws);
            const float f7 = fmaf((float)q1[3], ws, m8ws);
            bu.h[0] = __float22bfloat162_rn(float2{f0, f1});
            bu.h[1] = __float22bfloat162_rn(float2{f2, f3});
            bu.h[2] = __float22bfloat162_rn(float2{f4, f5});
            bu.h[3] = __float22bfloat162_rn(float2{f6, f7});

            acc = __builtin_amdgcn_mfma_f32_32x32x16_bf16(a, bu.v, acc, 0, 0, 0);
        }
    }

    // Epilogue: raw partial stores (every element of this ky-slice written
    // exactly once -> no init, no atomics). Nontemporal: don't pollute L2.
    float* __restrict__ pp =
        partials + ((size_t)blockIdx.y * Mdim) * Ndim + col;
    const int rbase = (lane >> 5) * 4;
#pragma unroll
    for (int r = 0; r < 16; ++r) {
        const int row = (r & 3) + 8 * (r >> 2) + rbase;
        __builtin_nontemporal_store(acc[r], pp + (size_t)row * Ndim);
    }
}

// ---------------------------------------------------------------------------
// Kernel 3: out[m][n] = bias[n] + scales[m] * sum_ky partials[ky][m][n]
// grid = (Ndim/4/256 = 14, Mdim), 256 threads, float4 per thread.
// ---------------------------------------------------------------------------
__global__ __launch_bounds__(256) void reduce_kernel(
        const float* __restrict__ partials, const float* __restrict__ scales,
        const float* __restrict__ bias, float* __restrict__ out) {
    const int n4 = blockIdx.x * 256 + threadIdx.x;   // float4 index within row
    const int m  = blockIdx.y;
    const size_t row4 = (size_t)m * (Ndim / 4) + n4;

    float4 s = {0.f, 0.f, 0.f, 0.f};
#pragma unroll
    for (int ky = 0; ky < KB; ++ky) {
        const float4 p = ((const float4*)partials)[(size_t)ky * Mdim * (Ndim / 4) + row4];
        s.x += p.x; s.y += p.y; s.z += p.z; s.w += p.w;
    }
    const float sc = scales[m];
    const float4 b = ((const float4*)bias)[n4];
    float4 o;
    o.x = fmaf(sc, s.x, b.x);
    o.y = fmaf(sc, s.y, b.y);
    o.z = fmaf(sc, s.z, b.z);
    o.w = fmaf(sc, s.w, b.w);
    ((float4*)out)[row4] = o;
}

// ---------------------------------------------------------------------------
extern "C" void kernel_launch(void* const* d_in, const int* in_sizes, int n_in,
                              void* d_out, int out_size, void* d_ws, size_t ws_size,
                              hipStream_t stream) {
    const float* x    = (const float*)d_in[0];
    const int*   qw   = (const int*)d_in[1];
    const float* wsc  = (const float*)d_in[2];
    const float* bias = (const float*)d_in[3];
    float* out = (float*)d_out;

    // ws layout: [0,128): row scales; [256, 256+512K): xq bf16;
    //            [1M, 1M+14.7M): partials f32 [KB][Mdim][Ndim]
    float* scales = (float*)d_ws;
    __hip_bfloat16* xq = (__hip_bfloat16*)((char*)d_ws + 256);
    float* partials = (float*)((char*)d_ws + (1u << 20));

    quant_rows_kernel<<<Mdim, 256, 0, stream>>>(x, xq, scales);
    qlin_main_kernel<<<dim3(Ndim / BN, KB), 128, 0, stream>>>(qw, wsc, xq, partials);
    reduce_kernel<<<dim3(Ndim / 4 / 256, Mdim), 256, 0, stream>>>(partials, scales, bias, out);
}

// Round 8
// 624.259 us; speedup vs baseline: 1.0426x; 1.0426x over previous
//
#include <hip/hip_runtime.h>
#include <hip/hip_bf16.h>

// Problem dims (fixed by setup_inputs)
#define Mdim 32
#define Kdim 8192
#define Ndim 14336
#define GSZ  128
#define NGRP 64      // Kdim / GSZ

#define KB 8         // K-split factor (chunks of the K dim across blockIdx.y)
#define KC (Kdim/KB) // 1024 = 8 groups of 128
#define BN 64        // n-columns per workgroup (2 waves x 32 cols)

typedef __attribute__((ext_vector_type(16))) float f32x16;
typedef __attribute__((ext_vector_type(8)))  short bf16x8;
typedef __attribute__((ext_vector_type(4)))  int   i32x4;

// ---------------------------------------------------------------------------
// Kernel 1: per-row asymmetric 8-bit quant of x -> (qx - zp) as exact bf16
// integers + per-row scale; also initializes out[row][:] = bias (atomic
// epilogue accumulates into it; d_out is re-poisoned before every launch).
// ---------------------------------------------------------------------------
__global__ __launch_bounds__(256) void quant_rows_kernel(
        const float* __restrict__ x,
        const float* __restrict__ bias,
        __hip_bfloat16* __restrict__ xq,
        float* __restrict__ scales,
        float* __restrict__ out) {
    const int row = blockIdx.x;
    const float4* __restrict__ xr4 = (const float4*)(x + (size_t)row * Kdim);

    float lmin = 3.4e38f, lmax = -3.4e38f;
#pragma unroll
    for (int i = 0; i < Kdim / 4 / 256; ++i) {           // 8 float4 per thread
        const float4 v = xr4[threadIdx.x + i * 256];
        lmin = fminf(lmin, fminf(fminf(v.x, v.y), fminf(v.z, v.w)));
        lmax = fmaxf(lmax, fmaxf(fmaxf(v.x, v.y), fmaxf(v.z, v.w)));
    }
#pragma unroll
    for (int off = 32; off > 0; off >>= 1) {
        lmin = fminf(lmin, __shfl_xor(lmin, off, 64));
        lmax = fmaxf(lmax, __shfl_xor(lmax, off, 64));
    }
    __shared__ float smin[4], smax[4];
    const int wid = threadIdx.x >> 6;
    if ((threadIdx.x & 63) == 0) { smin[wid] = lmin; smax[wid] = lmax; }
    __syncthreads();
    const float xmin = fminf(fminf(smin[0], smin[1]), fminf(smin[2], smin[3]));
    const float xmax = fmaxf(fmaxf(smax[0], smax[1]), fmaxf(smax[2], smax[3]));

    const float scale = fmaxf((xmax - xmin) / 255.0f, 1e-8f);
    float zp = rintf(-128.0f - xmin / scale);   // jnp.round == rintf (half-even)
    zp = fminf(fmaxf(zp, -128.0f), 127.0f);
    if (threadIdx.x == 0) scales[row] = scale;

    ushort4* __restrict__ xq4 = (ushort4*)(xq + (size_t)row * Kdim);
#pragma unroll
    for (int i = 0; i < Kdim / 4 / 256; ++i) {
        const float4 v = xr4[threadIdx.x + i * 256];
        ushort4 o;
        float q;
        q = fminf(fmaxf(rintf(v.x / scale) + zp, -128.0f), 127.0f);
        o.x = __bfloat16_as_ushort(__float2bfloat16(q - zp)); // exact: |.|<=255
        q = fminf(fmaxf(rintf(v.y / scale) + zp, -128.0f), 127.0f);
        o.y = __bfloat16_as_ushort(__float2bfloat16(q - zp));
        q = fminf(fmaxf(rintf(v.z / scale) + zp, -128.0f), 127.0f);
        o.z = __bfloat16_as_ushort(__float2bfloat16(q - zp));
        q = fminf(fmaxf(rintf(v.w / scale) + zp, -128.0f), 127.0f);
        o.w = __bfloat16_as_ushort(__float2bfloat16(q - zp));
        xq4[threadIdx.x + i * 256] = o;
    }

    // out[row][:] = bias
    const float4* __restrict__ b4 = (const float4*)bias;
    float4* __restrict__ o4 = (float4*)(out + (size_t)row * Ndim);
#pragma unroll
    for (int i = 0; i < Ndim / 4 / 256; ++i)             // 14 float4 per thread
        o4[threadIdx.x + i * 256] = b4[threadIdx.x + i * 256];
}

// ---------------------------------------------------------------------------
// Kernel 2: streaming GEMM. grid = (224, 8), 128 threads (2 waves). Each
// wave: 32x32 output tile, K-chunk 1024. Per GROUP (128 codes) all loads are
// batch-issued first — 8 a-frags (L2-resident xq), then 16 weight dwordx4 —
// so ~16 HBM lines/wave stay in flight while the 8 MFMA steps consume them
// via counted vmcnt waits. This is the MLP fix: 16-B-per-lane loads with a
// 3-deep queue could not fill the ~9 KB/CU outstanding-bytes requirement of
// 6.3 TB/s at ~900-cycle HBM latency.
// MFMA fragment layouts (gfx950, 32x32x16 bf16):
//   A: row = lane&31, k = 8*(lane>>5)+e   (8 contiguous bf16 per lane)
//   B: col = lane&31, k = 8*(lane>>5)+e
//   C/D: col = lane&31, row = (reg&3) + 8*(reg>>2) + 4*(lane>>5)
// ---------------------------------------------------------------------------
__global__ __launch_bounds__(128) void qlin_main_kernel(
        const int* __restrict__ qw, const float* __restrict__ wscale,
        const __hip_bfloat16* __restrict__ xq, const float* __restrict__ scales,
        float* __restrict__ out) {
    const int lane  = threadIdx.x & 63;
    const int wid   = threadIdx.x >> 6;
    const int col   = blockIdx.x * BN + wid * 32 + (lane & 31);
    const int k0    = blockIdx.y * KC;
    const int khalf = (lane >> 5) * 8;

    const int* __restrict__ wp = qw + (size_t)col * Kdim + k0 + khalf;
    const __hip_bfloat16* __restrict__ ap =
        xq + (size_t)(lane & 31) * Kdim + k0 + khalf;
    const float* __restrict__ wsp = wscale + (size_t)col * NGRP + (k0 / GSZ);

    f32x16 acc = {};

    for (int g = 0; g < KC / GSZ; ++g) {          // 8 weight groups per chunk
        const float ws   = wsp[g];
        const float m8ws = -8.0f * ws;
        const int* __restrict__ wpg = wp + g * GSZ;
        const __hip_bfloat16* __restrict__ apg = ap + g * GSZ;

        // ---- batch-issue phase: a-frags first (L2 hits, drained first),
        // ---- then the 16 HBM weight loads back-to-back.
        bf16x8 a[8];
#pragma unroll
        for (int s = 0; s < 8; ++s)
            a[s] = *(const bf16x8*)(apg + s * 16);
        i32x4 q[16];
#pragma unroll
        for (int s = 0; s < 8; ++s) {
            q[2 * s]     = *(const i32x4*)(wpg + s * 16);
            q[2 * s + 1] = *(const i32x4*)(wpg + s * 16 + 4);
        }

        // ---- compute phase: 8 MFMA K-steps, consuming q[] in issue order
#pragma unroll
        for (int s = 0; s < 8; ++s) {
            const i32x4 q0 = q[2 * s];
            const i32x4 q1 = q[2 * s + 1];
            union { bf16x8 v; __hip_bfloat162 h[4]; } bu;
            const float f0 = fmaf((float)q0[0], ws, m8ws);
            const float f1 = fmaf((float)q0[1], ws, m8ws);
            const float f2 = fmaf((float)q0[2], ws, m8ws);
            const float f3 = fmaf((float)q0[3], ws, m8ws);
            const float f4 = fmaf((float)q1[0], ws, m8ws);
            const float f5 = fmaf((float)q1[1], ws, m8ws);
            const float f6 = fmaf((float)q1[2], ws, m8ws);
            const float f7 = fmaf((float)q1[3], ws, m8ws);
            bu.h[0] = __float22bfloat162_rn(float2{f0, f1});
            bu.h[1] = __float22bfloat162_rn(float2{f2, f3});
            bu.h[2] = __float22bfloat162_rn(float2{f4, f5});
            bu.h[3] = __float22bfloat162_rn(float2{f6, f7});

            acc = __builtin_amdgcn_mfma_f32_32x32x16_bf16(a[s], bu.v, acc, 0, 0, 0);
        }
    }

    // Epilogue: out[row][col] += scale_row * acc   (8-way K-split, hidden
    // behind other blocks' streaming; measured cheaper than partials+reduce)
    const int rbase = (lane >> 5) * 4;
    const float4 s0 = *(const float4*)(scales + rbase);
    const float4 s1 = *(const float4*)(scales + rbase + 8);
    const float4 s2 = *(const float4*)(scales + rbase + 16);
    const float4 s3 = *(const float4*)(scales + rbase + 24);
    const float sr[16] = {s0.x, s0.y, s0.z, s0.w, s1.x, s1.y, s1.z, s1.w,
                          s2.x, s2.y, s2.z, s2.w, s3.x, s3.y, s3.z, s3.w};
#pragma unroll
    for (int r = 0; r < 16; ++r) {
        const int row = (r & 3) + 8 * (r >> 2) + rbase;
        unsafeAtomicAdd(out + (size_t)row * Ndim + col, sr[r] * acc[r]);
    }
}

// ---------------------------------------------------------------------------
extern "C" void kernel_launch(void* const* d_in, const int* in_sizes, int n_in,
                              void* d_out, int out_size, void* d_ws, size_t ws_size,
                              hipStream_t stream) {
    const float* x    = (const float*)d_in[0];
    const int*   qw   = (const int*)d_in[1];
    const float* wsc  = (const float*)d_in[2];
    const float* bias = (const float*)d_in[3];
    float* out = (float*)d_out;

    // ws layout: [0,128): row scales (32 f32); [256, 256+512K): xq bf16
    float* scales = (float*)d_ws;
    __hip_bfloat16* xq = (__hip_bfloat16*)((char*)d_ws + 256);

    quant_rows_kernel<<<Mdim, 256, 0, stream>>>(x, bias, xq, scales, out);
    qlin_main_kernel<<<dim3(Ndim / BN, KB), 128, 0, stream>>>(qw, wsc, xq, scales, out);
}